// Round 1
// baseline (684.499 us; speedup 1.0000x reference)
//
#include <hip/hip_runtime.h>
#include <math.h>

#define BTOT 16384

// Contract two 16-dim nodes with a 16x16x16 weight tensor.
// l: register array (i fully unrolled -> constant indexing, stays in VGPRs)
// col: per-thread LDS column, col[j*256] = r[j]  (j rolled -> dynamic index ok in LDS)
// Wp: wave-uniform address -> scalar loads (s_load_dwordx16 per (i,j))
__device__ __forceinline__ void contract16(const float* __restrict__ Wp,
                                           const float* l, const float* col,
                                           float* out) {
#pragma unroll
  for (int d = 0; d < 16; ++d) out[d] = 0.f;
#pragma unroll
  for (int i = 0; i < 16; ++i) {
    const float li = l[i];
    for (int j = 0; j < 16; ++j) {
      const float p = li * col[j * 256];
      const float* w = Wp + (i * 16 + j) * 16;
#pragma unroll
      for (int d = 0; d < 16; ++d) out[d] = fmaf(p, w[d], out[d]);
    }
  }
}

__device__ __forceinline__ void feats_to_regs(float x, float* f) {
  float s1 = __sinf(x), c1 = __cosf(x);
  f[0] = 1.f; f[1] = s1; f[5] = c1;
  float sk = s1, ck = c1;
#pragma unroll
  for (int k = 2; k <= 4; ++k) {
    float sn = s1 * ck + c1 * sk;
    float cn = c1 * ck - s1 * sk;
    sk = sn; ck = cn;
    f[k] = sk; f[4 + k] = ck;
  }
}

// Levels 0-3 fused: one thread = one (batch, subtree-of-16-leaves), depth-first.
// Output layout: out[(s*16 + d)*BTOT + b]   (coalesced stores, coalesced next-level loads)
__global__ __launch_bounds__(256) void stage1_kernel(
    const float* __restrict__ x, const float* __restrict__ fminp,
    const float* __restrict__ W0, const float* __restrict__ W1,
    const float* __restrict__ W2, const float* __restrict__ W3,
    float* __restrict__ out) {
  __shared__ float rbuf[16][256];
  const int tid = threadIdx.x;
  const int b = blockIdx.x * 256 + tid;
  const int s = blockIdx.y;           // subtree 0..15 (uniform per block)
  const float fmin = fminp[0];
  const float* xr = x + (size_t)b * 256 + s * 16;
  float* col = &rbuf[0][tid];

  float st0[16], st1[16], st2[16], cur[16];

  for (int t = 0; t < 8; ++t) {       // 8 leaf-pairs of this subtree
    float2 xv = *(const float2*)(xr + 2 * t);
    // left-leaf feats in registers, right-leaf feats into LDS column
    float fa[9];
    feats_to_regs(xv.x * fmin, fa);
    {
      float xb = xv.y * fmin;
      float s1 = __sinf(xb), c1 = __cosf(xb);
      rbuf[0][tid] = 1.f; rbuf[1][tid] = s1; rbuf[5][tid] = c1;
      float sk = s1, ck = c1;
#pragma unroll
      for (int k = 2; k <= 4; ++k) {
        float sn = s1 * ck + c1 * sk;
        float cn = c1 * ck - s1 * sk;
        sk = sn; ck = cn;
        rbuf[k][tid] = sk; rbuf[4 + k][tid] = ck;
      }
    }
    // level 0 contract: 9x9x16, node index n0 = 8*s + t
    {
      const float* Wp = W0 + (size_t)(8 * s + t) * (9 * 9 * 16);
#pragma unroll
      for (int d = 0; d < 16; ++d) cur[d] = 0.f;
#pragma unroll
      for (int i = 0; i < 9; ++i) {
        const float li = fa[i];
        for (int j = 0; j < 9; ++j) {
          const float p = li * col[j * 256];
          const float* w = Wp + (i * 9 + j) * 16;
#pragma unroll
          for (int d = 0; d < 16; ++d) cur[d] = fmaf(p, w[d], cur[d]);
        }
      }
    }
    // depth-first combine up the subtree
    if ((t & 1) == 0) {
#pragma unroll
      for (int d = 0; d < 16; ++d) st0[d] = cur[d];
    } else {
#pragma unroll
      for (int d = 0; d < 16; ++d) rbuf[d][tid] = cur[d];
      float c1v[16];
      contract16(W1 + (size_t)(4 * s + (t >> 1)) * 4096, st0, col, c1v);
      if ((t & 2) == 0) {
#pragma unroll
        for (int d = 0; d < 16; ++d) st1[d] = c1v[d];
      } else {
#pragma unroll
        for (int d = 0; d < 16; ++d) rbuf[d][tid] = c1v[d];
        float c2v[16];
        contract16(W2 + (size_t)(2 * s + (t >> 2)) * 4096, st1, col, c2v);
        if ((t & 4) == 0) {
#pragma unroll
          for (int d = 0; d < 16; ++d) st2[d] = c2v[d];
        } else {
#pragma unroll
          for (int d = 0; d < 16; ++d) rbuf[d][tid] = c2v[d];
          float c3v[16];
          contract16(W3 + (size_t)s * 4096, st2, col, c3v);
#pragma unroll
          for (int d = 0; d < 16; ++d)
            out[((size_t)(s * 16 + d)) * BTOT + b] = c3v[d];
        }
      }
    }
  }
}

// One level of 16x16x16 contractions: thread = (b, node), node = blockIdx.y (uniform).
// in layout: [node][dim][BTOT], out layout: [node][dim][BTOT]
__global__ __launch_bounds__(256) void level16_kernel(
    const float* __restrict__ in, const float* __restrict__ W,
    float* __restrict__ out) {
  __shared__ float rbuf[16][256];
  const int tid = threadIdx.x;
  const int b = blockIdx.x * 256 + tid;
  const int n = blockIdx.y;
  float* col = &rbuf[0][tid];
  float l[16];
#pragma unroll
  for (int d = 0; d < 16; ++d) {
    l[d] = in[((size_t)(2 * n) * 16 + d) * BTOT + b];
    rbuf[d][tid] = in[((size_t)(2 * n + 1) * 16 + d) * BTOT + b];
  }
  float acc[16];
  contract16(W + (size_t)n * 4096, l, col, acc);
#pragma unroll
  for (int d = 0; d < 16; ++d) out[((size_t)(n * 16 + d)) * BTOT + b] = acc[d];
}

// Final level: 16x16x1, thread per b. W7 is (1,16,16,1) -> W[i*16+j].
__global__ __launch_bounds__(256) void final_kernel(
    const float* __restrict__ in, const float* __restrict__ W,
    float* __restrict__ out) {
  const int b = blockIdx.x * 256 + threadIdx.x;
  float l[16], r[16];
#pragma unroll
  for (int d = 0; d < 16; ++d) {
    l[d] = in[(size_t)d * BTOT + b];
    r[d] = in[(size_t)(16 + d) * BTOT + b];
  }
  float acc = 0.f;
#pragma unroll
  for (int i = 0; i < 16; ++i)
#pragma unroll
    for (int j = 0; j < 16; ++j)
      acc = fmaf(l[i] * r[j], W[i * 16 + j], acc);
  out[b] = acc;
}

extern "C" void kernel_launch(void* const* d_in, const int* in_sizes, int n_in,
                              void* d_out, int out_size, void* d_ws, size_t ws_size,
                              hipStream_t stream) {
  const float* x    = (const float*)d_in[0];
  const float* fmin = (const float*)d_in[1];
  const float* W0   = (const float*)d_in[2];
  const float* W1   = (const float*)d_in[3];
  const float* W2   = (const float*)d_in[4];
  const float* W3   = (const float*)d_in[5];
  const float* W4   = (const float*)d_in[6];
  const float* W5   = (const float*)d_in[7];
  const float* W6   = (const float*)d_in[8];
  const float* W7   = (const float*)d_in[9];
  float* out = (float*)d_out;

  float* ws = (float*)d_ws;
  float* s1 = ws;                        // 16*16*BTOT floats (16.8 MB)
  float* l4 = s1 + (size_t)16 * 16 * BTOT; //  8*16*BTOT
  float* l5 = l4 + (size_t)8 * 16 * BTOT;  //  4*16*BTOT
  float* l6 = l5 + (size_t)4 * 16 * BTOT;  //  2*16*BTOT

  dim3 blk(256);
  stage1_kernel<<<dim3(BTOT / 256, 16), blk, 0, stream>>>(x, fmin, W0, W1, W2, W3, s1);
  level16_kernel<<<dim3(BTOT / 256, 8), blk, 0, stream>>>(s1, W4, l4);
  level16_kernel<<<dim3(BTOT / 256, 4), blk, 0, stream>>>(l4, W5, l5);
  level16_kernel<<<dim3(BTOT / 256, 2), blk, 0, stream>>>(l5, W6, l6);
  final_kernel<<<BTOT / 256, blk, 0, stream>>>(l6, W7, out);
}

// Round 2
// 560.098 us; speedup vs baseline: 1.2221x; 1.2221x over previous
//
#include <hip/hip_runtime.h>
#include <math.h>

#define BTOT 16384

// Contract two 16-dim nodes with a 16x16x16 weight tensor.
// j OUTER rolled: one dynamic LDS read of r_j feeds 272 unrolled FMAs.
// l: register array (constant-indexed), col: per-thread LDS column col[j*NT].
// Wp wave-uniform -> scalar loads; each (i,j) row is one aligned 64B line.
template <int NT>
__device__ __forceinline__ void contract16(const float* __restrict__ Wp,
                                           const float* l, const float* col,
                                           float* out) {
#pragma unroll
  for (int d = 0; d < 16; ++d) out[d] = 0.f;
  for (int j = 0; j < 16; ++j) {        // rolled
    const float rj = col[j * NT];       // 1 ds_read per 272 VALU
    const float* w = Wp + j * 16;       // w[i*256 + d] == Wp[(i*16+j)*16+d]
#pragma unroll
    for (int i = 0; i < 16; ++i) {
      const float p = l[i] * rj;
#pragma unroll
      for (int d = 0; d < 16; ++d) out[d] = fmaf(p, w[i * 256 + d], out[d]);
    }
  }
}

__device__ __forceinline__ void feats_to_regs(float x, float* f) {
  float s1 = __sinf(x), c1 = __cosf(x);
  f[0] = 1.f; f[1] = s1; f[5] = c1;
  float sk = s1, ck = c1;
#pragma unroll
  for (int k = 2; k <= 4; ++k) {
    float sn = s1 * ck + c1 * sk;
    float cn = c1 * ck - s1 * sk;
    sk = sn; ck = cn;
    f[k] = sk; f[4 + k] = ck;
  }
}

// Levels 0-3 fused: one thread = one (batch, subtree-of-16-leaves), depth-first.
// NT=128 threads/block -> 2048 blocks -> 8 blocks/CU.
// Output layout: out[(s*16 + d)*BTOT + b]
__global__ __launch_bounds__(128) void stage1_kernel(
    const float* __restrict__ x, const float* __restrict__ fminp,
    const float* __restrict__ W0, const float* __restrict__ W1,
    const float* __restrict__ W2, const float* __restrict__ W3,
    float* __restrict__ out) {
  constexpr int NT = 128;
  __shared__ float rbuf[16][NT];
  const int tid = threadIdx.x;
  const int b = blockIdx.x * NT + tid;
  const int s = blockIdx.y;             // subtree 0..15 (uniform per block)
  const float fmin = fminp[0];
  const float* xr = x + (size_t)b * 256 + s * 16;
  float* col = &rbuf[0][tid];

  float st0[16], st1[16], st2[16], cur[16];

  for (int t = 0; t < 8; ++t) {         // 8 leaf-pairs; branches are t-uniform
    float2 xv = *(const float2*)(xr + 2 * t);
    float fa[9];
    feats_to_regs(xv.x * fmin, fa);
    {
      float xb = xv.y * fmin;
      float s1 = __sinf(xb), c1 = __cosf(xb);
      rbuf[0][tid] = 1.f; rbuf[1][tid] = s1; rbuf[5][tid] = c1;
      float sk = s1, ck = c1;
#pragma unroll
      for (int k = 2; k <= 4; ++k) {
        float sn = s1 * ck + c1 * sk;
        float cn = c1 * ck - s1 * sk;
        sk = sn; ck = cn;
        rbuf[k][tid] = sk; rbuf[4 + k][tid] = ck;
      }
    }
    // level 0: 9x9x16 contract, node n0 = 8*s + t, j outer rolled
    {
      const float* Wp = W0 + (size_t)(8 * s + t) * (9 * 9 * 16);
#pragma unroll
      for (int d = 0; d < 16; ++d) cur[d] = 0.f;
      for (int j = 0; j < 9; ++j) {
        const float rj = col[j * NT];
        const float* w = Wp + j * 16;   // w[i*144 + d] == Wp[(i*9+j)*16+d]
#pragma unroll
        for (int i = 0; i < 9; ++i) {
          const float p = fa[i] * rj;
#pragma unroll
          for (int d = 0; d < 16; ++d) cur[d] = fmaf(p, w[i * 144 + d], cur[d]);
        }
      }
    }
    // depth-first combine up the subtree (t-uniform branching)
    if ((t & 1) == 0) {
#pragma unroll
      for (int d = 0; d < 16; ++d) st0[d] = cur[d];
    } else {
#pragma unroll
      for (int d = 0; d < 16; ++d) rbuf[d][tid] = cur[d];
      float c1v[16];
      contract16<NT>(W1 + (size_t)(4 * s + (t >> 1)) * 4096, st0, col, c1v);
      if ((t & 2) == 0) {
#pragma unroll
        for (int d = 0; d < 16; ++d) st1[d] = c1v[d];
      } else {
#pragma unroll
        for (int d = 0; d < 16; ++d) rbuf[d][tid] = c1v[d];
        float c2v[16];
        contract16<NT>(W2 + (size_t)(2 * s + (t >> 2)) * 4096, st1, col, c2v);
        if ((t & 4) == 0) {
#pragma unroll
          for (int d = 0; d < 16; ++d) st2[d] = c2v[d];
        } else {
#pragma unroll
          for (int d = 0; d < 16; ++d) rbuf[d][tid] = c2v[d];
          float c3v[16];
          contract16<NT>(W3 + (size_t)s * 4096, st2, col, c3v);
#pragma unroll
          for (int d = 0; d < 16; ++d)
            out[((size_t)(s * 16 + d)) * BTOT + b] = c3v[d];
        }
      }
    }
  }
}

// One level of 16x16x16 contractions: thread = (b, node), node = blockIdx.y.
__global__ __launch_bounds__(128) void level16_kernel(
    const float* __restrict__ in, const float* __restrict__ W,
    float* __restrict__ out) {
  constexpr int NT = 128;
  __shared__ float rbuf[16][NT];
  const int tid = threadIdx.x;
  const int b = blockIdx.x * NT + tid;
  const int n = blockIdx.y;
  float* col = &rbuf[0][tid];
  float l[16];
#pragma unroll
  for (int d = 0; d < 16; ++d) {
    l[d] = in[((size_t)(2 * n) * 16 + d) * BTOT + b];
    rbuf[d][tid] = in[((size_t)(2 * n + 1) * 16 + d) * BTOT + b];
  }
  float acc[16];
  contract16<NT>(W + (size_t)n * 4096, l, col, acc);
#pragma unroll
  for (int d = 0; d < 16; ++d) out[((size_t)(n * 16 + d)) * BTOT + b] = acc[d];
}

// Final level: 16x16x1, thread per b.
__global__ __launch_bounds__(256) void final_kernel(
    const float* __restrict__ in, const float* __restrict__ W,
    float* __restrict__ out) {
  const int b = blockIdx.x * 256 + threadIdx.x;
  float l[16], r[16];
#pragma unroll
  for (int d = 0; d < 16; ++d) {
    l[d] = in[(size_t)d * BTOT + b];
    r[d] = in[(size_t)(16 + d) * BTOT + b];
  }
  float acc = 0.f;
#pragma unroll
  for (int i = 0; i < 16; ++i)
#pragma unroll
    for (int j = 0; j < 16; ++j)
      acc = fmaf(l[i] * r[j], W[i * 16 + j], acc);
  out[b] = acc;
}

extern "C" void kernel_launch(void* const* d_in, const int* in_sizes, int n_in,
                              void* d_out, int out_size, void* d_ws, size_t ws_size,
                              hipStream_t stream) {
  const float* x    = (const float*)d_in[0];
  const float* fmin = (const float*)d_in[1];
  const float* W0   = (const float*)d_in[2];
  const float* W1   = (const float*)d_in[3];
  const float* W2   = (const float*)d_in[4];
  const float* W3   = (const float*)d_in[5];
  const float* W4   = (const float*)d_in[6];
  const float* W5   = (const float*)d_in[7];
  const float* W6   = (const float*)d_in[8];
  const float* W7   = (const float*)d_in[9];
  float* out = (float*)d_out;

  float* ws = (float*)d_ws;
  float* s1 = ws;                          // 16*16*BTOT floats (16.8 MB)
  float* l4 = s1 + (size_t)16 * 16 * BTOT; //  8*16*BTOT
  float* l5 = l4 + (size_t)8 * 16 * BTOT;  //  4*16*BTOT
  float* l6 = l5 + (size_t)4 * 16 * BTOT;  //  2*16*BTOT

  stage1_kernel<<<dim3(BTOT / 128, 16), dim3(128), 0, stream>>>(x, fmin, W0, W1, W2, W3, s1);
  level16_kernel<<<dim3(BTOT / 128, 8), dim3(128), 0, stream>>>(s1, W4, l4);
  level16_kernel<<<dim3(BTOT / 128, 4), dim3(128), 0, stream>>>(l4, W5, l5);
  level16_kernel<<<dim3(BTOT / 128, 2), dim3(128), 0, stream>>>(l5, W6, l6);
  final_kernel<<<BTOT / 256, dim3(256), 0, stream>>>(l6, W7, out);
}

// Round 3
// 410.305 us; speedup vs baseline: 1.6683x; 1.3651x over previous
//
#include <hip/hip_runtime.h>
#include <math.h>

#define BTOT 16384

typedef __attribute__((ext_vector_type(8))) short s16x8;
typedef __attribute__((ext_vector_type(4))) float f32x4;

__device__ __forceinline__ ushort rtn_bf16(float x) {
  uint u = __builtin_bit_cast(uint, x);
  uint r = u + 0x7fffu + ((u >> 16) & 1u);
  return (ushort)(r >> 16);
}

// ---------------- W-frag prep: convert W0..W3 to MFMA B-frag order, bf16 hi/lo ----
// Frag entry (kt, lane, jv): k = kt*32 + (lane>>4)*8 + jv; B[k][n=lane&15].
// Blob layout per node: [entries hi ushort][entries lo ushort], entries = ktN*512.
__global__ __launch_bounds__(256) void wprep_kernel(
    const float* __restrict__ W0, const float* __restrict__ W1,
    const float* __restrict__ W2, const float* __restrict__ W3,
    ushort* __restrict__ U) {
  int blk = blockIdx.x;
  const float* Wsrc; ushort* dst; int ktN, din;
  if (blk < 128)      { Wsrc = W0 + blk * 1296;         dst = U + (size_t)blk * 5120;                   ktN = 5; din = 9;  }
  else if (blk < 192) { Wsrc = W1 + (blk - 128) * 4096; dst = U + 655360 + (size_t)(blk - 128) * 8192;  ktN = 8; din = 16; }
  else if (blk < 224) { Wsrc = W2 + (blk - 192) * 4096; dst = U + 1179648 + (size_t)(blk - 192) * 8192; ktN = 8; din = 16; }
  else                { Wsrc = W3 + (blk - 224) * 4096; dst = U + 1441792 + (size_t)(blk - 224) * 8192; ktN = 8; din = 16; }
  int entries = ktN * 512;
  for (int e = threadIdx.x; e < entries; e += 256) {
    int kt = e >> 9, l = (e >> 3) & 63, jv = e & 7;
    int k = kt * 32 + ((l >> 4) << 3) + jv;
    int i = k >> 4, j = k & 15, n = l & 15;
    float w = (i < din && j < din) ? Wsrc[(i * din + j) * 16 + n] : 0.f;
    uint u = __builtin_bit_cast(uint, w);
    uint h = u & 0xffff0000u;
    dst[e] = (ushort)(h >> 16);
    dst[entries + e] = rtn_bf16(w - __builtin_bit_cast(float, h));
  }
}

// ---------------- MFMA bilinear task -------------------------------------------
// One wave computes out[16 b][16 d] for one node. Lb/Rb: LDS [dim][68] fp32.
// A[m][k] = l_i * r_j (k = i*16+j) built in-register, split hi/lo bf16 exactly.
template <int KTN, bool L0M, bool GOUT>
__device__ __forceinline__ void mfma_task(
    const float* Lb, const float* Rb, const ushort* Wf, int tid,
    float* OutL, float* __restrict__ outG) {
  const int lane = tid & 63, w = tid >> 6;
  const int m = lane & 15, g = lane >> 4;
  const int bl = w * 16 + m;
  const int j0 = (g & 1) * 8;
  const int gh = g >> 1;
  float lf[2 * KTN];
#pragma unroll
  for (int i = 0; i < 2 * KTN; ++i) lf[i] = Lb[i * 68 + bl];
  float rf[8];
#pragma unroll
  for (int j = 0; j < 8; ++j) {
    if (L0M) rf[j] = (j0 + j < 9) ? Rb[(j0 + j) * 68 + bl] : 0.f;
    else     rf[j] = Rb[(j0 + j) * 68 + bl];
  }
  f32x4 acc = {0.f, 0.f, 0.f, 0.f};
  const int entries = KTN * 512;
#pragma unroll
  for (int kt = 0; kt < KTN; ++kt) {
    const float li = lf[2 * kt + gh];
    s16x8 ahi, alo;
#pragma unroll
    for (int j = 0; j < 8; ++j) {
      float p = li * rf[j];
      uint u = __builtin_bit_cast(uint, p);
      uint h = u & 0xffff0000u;
      ahi[j] = (short)(ushort)(h >> 16);
      alo[j] = (short)rtn_bf16(p - __builtin_bit_cast(float, h));
    }
    const s16x8 wh = *(const s16x8*)&Wf[(kt * 64 + lane) * 8];
    const s16x8 wl = *(const s16x8*)&Wf[entries + (kt * 64 + lane) * 8];
    acc = __builtin_amdgcn_mfma_f32_16x16x32_bf16(ahi, wh, acc, 0, 0, 0);
    acc = __builtin_amdgcn_mfma_f32_16x16x32_bf16(alo, wh, acc, 0, 0, 0);
    acc = __builtin_amdgcn_mfma_f32_16x16x32_bf16(ahi, wl, acc, 0, 0, 0);
  }
  // C/D: col(d) = lane&15, row(b) = g*4 + reg  [m89-verified]
  if (GOUT) {
#pragma unroll
    for (int r = 0; r < 4; ++r)
      outG[(size_t)m * BTOT + w * 16 + g * 4 + r] = acc[r];
  } else {
#pragma unroll
    for (int r = 0; r < 4; ++r)
      OutL[m * 68 + w * 16 + g * 4 + r] = acc[r];
  }
}

__device__ __forceinline__ void feats_store(float xv, float* Fb, int bl) {
  float s1 = __sinf(xv), c1 = __cosf(xv);
  Fb[0 * 68 + bl] = 1.f; Fb[1 * 68 + bl] = s1; Fb[5 * 68 + bl] = c1;
  float sk = s1, ck = c1;
#pragma unroll
  for (int k = 2; k <= 4; ++k) {
    float sn = s1 * ck + c1 * sk, cn = c1 * ck - s1 * sk;
    sk = sn; ck = cn;
    Fb[k * 68 + bl] = sk; Fb[(4 + k) * 68 + bl] = ck;
  }
}

__device__ __forceinline__ void wf_copy(ushort* Wf, const ushort* __restrict__ src,
                                        int n16, int tid) {
  const uint4* s = (const uint4*)src;
  uint4* d = (uint4*)Wf;
  for (int i = tid; i < n16; i += 256) d[i] = s[i];
}

// ---------------- Levels 0-3 fused, MFMA, depth-first --------------------------
// Block: 256 thr (4 waves), btile = 64 (wave w owns b-subtile w*16..), subtree s.
__global__ __launch_bounds__(256) void ttn_front_kernel(
    const float* __restrict__ x, const float* __restrict__ fminp,
    const ushort* __restrict__ U, float* __restrict__ s1out) {
  __shared__ __align__(16) float xt[64 * 17];
  __shared__ __align__(16) float F0[10 * 68], F1[10 * 68];
  __shared__ __align__(16) float A0[16 * 68], B0[16 * 68];
  __shared__ __align__(16) float A1[16 * 68], B1[16 * 68];
  __shared__ __align__(16) float A2[16 * 68], B2[16 * 68];
  __shared__ __align__(16) ushort Wf[8192];

  const int tid = threadIdx.x;
  const int bblk = blockIdx.x;   // 0..255
  const int s = blockIdx.y;      // 0..15
  const int b0 = bblk * 64;
  const float fmin = fminp[0];

  { // stage x tile [64 b][16 leaves], coalesced float4
    int b_l = tid >> 2, fq = tid & 3;
    float4 v = *(const float4*)&x[(size_t)(b0 + b_l) * 256 + s * 16 + fq * 4];
    xt[b_l * 17 + fq * 4 + 0] = v.x;
    xt[b_l * 17 + fq * 4 + 1] = v.y;
    xt[b_l * 17 + fq * 4 + 2] = v.z;
    xt[b_l * 17 + fq * 4 + 3] = v.w;
  }
  if (tid < 68)        F0[9 * 68 + tid] = 0.f;        // zero pad row (i=9)
  else if (tid < 136)  F1[9 * 68 + (tid - 68)] = 0.f;
  __syncthreads();

  const ushort* U0 = U;
  const ushort* U1 = U + 655360;
  const ushort* U2 = U + 1179648;
  const ushort* U3 = U + 1441792;
  float* outG = s1out + (size_t)(s * 16) * BTOT + b0;

  for (int t = 0; t < 8; ++t) {
    if (tid < 128) {
      int side = tid >> 6, bl = tid & 63;
      float xv = xt[bl * 17 + 2 * t + side] * fmin;
      feats_store(xv, side ? F1 : F0, bl);
    }
    wf_copy(Wf, U0 + (size_t)(8 * s + t) * 5120, 640, tid);
    __syncthreads();
    mfma_task<5, true, false>(F0, F1, Wf, tid, (t & 1) ? B0 : A0, nullptr);
    if (t & 1) {
      __syncthreads();
      wf_copy(Wf, U1 + (size_t)(4 * s + (t >> 1)) * 8192, 1024, tid);
      __syncthreads();
      mfma_task<8, false, false>(A0, B0, Wf, tid, ((t >> 1) & 1) ? B1 : A1, nullptr);
      if ((t & 3) == 3) {
        __syncthreads();
        wf_copy(Wf, U2 + (size_t)(2 * s + (t >> 2)) * 8192, 1024, tid);
        __syncthreads();
        mfma_task<8, false, false>(A1, B1, Wf, tid, ((t >> 2) & 1) ? B2 : A2, nullptr);
        if (t == 7) {
          __syncthreads();
          wf_copy(Wf, U3 + (size_t)s * 8192, 1024, tid);
          __syncthreads();
          mfma_task<8, false, true>(A2, B2, Wf, tid, nullptr, outG);
        }
      }
    }
    __syncthreads();   // guard next iter's F/Wf overwrite
  }
}

// ---------------- Backend levels 4-7 (VALU, unchanged from R2) -----------------
template <int NT>
__device__ __forceinline__ void contract16(const float* __restrict__ Wp,
                                           const float* l, const float* col,
                                           float* out) {
#pragma unroll
  for (int d = 0; d < 16; ++d) out[d] = 0.f;
  for (int j = 0; j < 16; ++j) {
    const float rj = col[j * NT];
    const float* w = Wp + j * 16;
#pragma unroll
    for (int i = 0; i < 16; ++i) {
      const float p = l[i] * rj;
#pragma unroll
      for (int d = 0; d < 16; ++d) out[d] = fmaf(p, w[i * 256 + d], out[d]);
    }
  }
}

__global__ __launch_bounds__(128) void level16_kernel(
    const float* __restrict__ in, const float* __restrict__ W,
    float* __restrict__ out) {
  constexpr int NT = 128;
  __shared__ float rbuf[16][NT];
  const int tid = threadIdx.x;
  const int b = blockIdx.x * NT + tid;
  const int n = blockIdx.y;
  float* col = &rbuf[0][tid];
  float l[16];
#pragma unroll
  for (int d = 0; d < 16; ++d) {
    l[d] = in[((size_t)(2 * n) * 16 + d) * BTOT + b];
    rbuf[d][tid] = in[((size_t)(2 * n + 1) * 16 + d) * BTOT + b];
  }
  float acc[16];
  contract16<NT>(W + (size_t)n * 4096, l, col, acc);
#pragma unroll
  for (int d = 0; d < 16; ++d) out[((size_t)(n * 16 + d)) * BTOT + b] = acc[d];
}

__global__ __launch_bounds__(256) void final_kernel(
    const float* __restrict__ in, const float* __restrict__ W,
    float* __restrict__ out) {
  const int b = blockIdx.x * 256 + threadIdx.x;
  float l[16], r[16];
#pragma unroll
  for (int d = 0; d < 16; ++d) {
    l[d] = in[(size_t)d * BTOT + b];
    r[d] = in[(size_t)(16 + d) * BTOT + b];
  }
  float acc = 0.f;
#pragma unroll
  for (int i = 0; i < 16; ++i)
#pragma unroll
    for (int j = 0; j < 16; ++j)
      acc = fmaf(l[i] * r[j], W[i * 16 + j], acc);
  out[b] = acc;
}

extern "C" void kernel_launch(void* const* d_in, const int* in_sizes, int n_in,
                              void* d_out, int out_size, void* d_ws, size_t ws_size,
                              hipStream_t stream) {
  const float* x    = (const float*)d_in[0];
  const float* fmin = (const float*)d_in[1];
  const float* W0   = (const float*)d_in[2];
  const float* W1   = (const float*)d_in[3];
  const float* W2   = (const float*)d_in[4];
  const float* W3   = (const float*)d_in[5];
  const float* W4   = (const float*)d_in[6];
  const float* W5   = (const float*)d_in[7];
  const float* W6   = (const float*)d_in[8];
  const float* W7   = (const float*)d_in[9];
  float* out = (float*)d_out;

  // ws layout: [0,4MB) W-frags | s1 16.8MB | l4 8.4MB ; l5 overlays s1, l6 overlays l4.
  ushort* U = (ushort*)d_ws;
  float* s1 = (float*)((char*)d_ws + (4u << 20));
  float* l4 = s1 + (size_t)16 * 16 * BTOT;
  float* l5 = s1;   // s1 dead after level-4 launch
  float* l6 = l4;   // l4 dead after level-5 launch

  wprep_kernel<<<240, 256, 0, stream>>>(W0, W1, W2, W3, U);
  ttn_front_kernel<<<dim3(256, 16), 256, 0, stream>>>(x, fmin, U, s1);
  level16_kernel<<<dim3(BTOT / 128, 8), dim3(128), 0, stream>>>(s1, W4, l4);
  level16_kernel<<<dim3(BTOT / 128, 4), dim3(128), 0, stream>>>(l4, W5, l5);
  level16_kernel<<<dim3(BTOT / 128, 2), dim3(128), 0, stream>>>(l5, W6, l6);
  final_kernel<<<BTOT / 256, dim3(256), 0, stream>>>(l6, W7, out);
}

// Round 4
// 379.779 us; speedup vs baseline: 1.8024x; 1.0804x over previous
//
#include <hip/hip_runtime.h>
#include <math.h>

#define BTOT 16384

typedef __attribute__((ext_vector_type(8))) short s16x8;
typedef __attribute__((ext_vector_type(4))) float f32x4;
typedef __attribute__((ext_vector_type(4))) uint u32x4;

// U region offsets (in ushorts). Per-node blob: [KTN*512 hi][KTN*512 lo].
#define OFF0 0u          // W0: 128 nodes x 5120
#define OFF1 655360u     // W1: 64 x 8192
#define OFF2 1179648u    // W2: 32 x 8192
#define OFF3 1441792u    // W3: 16 x 8192
#define OFF4 1572864u    // W4: 8 x 8192
#define OFF5 1638400u    // W5: 4 x 8192
#define OFF6 1671168u    // W6: 2 x 8192
#define OFF7 1687552u    // W7: 1 x 8192

__device__ __forceinline__ ushort rtn_bf16(float x) {
  uint u = __builtin_bit_cast(uint, x);
  uint r = u + 0x7fffu + ((u >> 16) & 1u);
  return (ushort)(r >> 16);
}

// ---------------- W-frag prep: all levels -> MFMA B-frag order, bf16 hi/lo ------
// Frag entry (kt, lane, jv): k = kt*32 + (lane>>4)*8 + jv; B[k][n=lane&15].
__global__ __launch_bounds__(256) void wprep_kernel(
    const float* __restrict__ W0, const float* __restrict__ W1,
    const float* __restrict__ W2, const float* __restrict__ W3,
    const float* __restrict__ W4, const float* __restrict__ W5,
    const float* __restrict__ W6, const float* __restrict__ W7,
    ushort* __restrict__ U) {
  int blk = blockIdx.x;
  const float* Wsrc; ushort* dst; int ktN, din; bool dout1 = false;
  if (blk < 128)      { Wsrc = W0 + blk * 1296;         dst = U + OFF0 + (size_t)blk * 5120;         ktN = 5; din = 9;  }
  else if (blk < 192) { Wsrc = W1 + (blk - 128) * 4096; dst = U + OFF1 + (size_t)(blk - 128) * 8192; ktN = 8; din = 16; }
  else if (blk < 224) { Wsrc = W2 + (blk - 192) * 4096; dst = U + OFF2 + (size_t)(blk - 192) * 8192; ktN = 8; din = 16; }
  else if (blk < 240) { Wsrc = W3 + (blk - 224) * 4096; dst = U + OFF3 + (size_t)(blk - 224) * 8192; ktN = 8; din = 16; }
  else if (blk < 248) { Wsrc = W4 + (blk - 240) * 4096; dst = U + OFF4 + (size_t)(blk - 240) * 8192; ktN = 8; din = 16; }
  else if (blk < 252) { Wsrc = W5 + (blk - 248) * 4096; dst = U + OFF5 + (size_t)(blk - 248) * 8192; ktN = 8; din = 16; }
  else if (blk < 254) { Wsrc = W6 + (blk - 252) * 4096; dst = U + OFF6 + (size_t)(blk - 252) * 8192; ktN = 8; din = 16; }
  else                { Wsrc = W7;                      dst = U + OFF7;                              ktN = 8; din = 16; dout1 = true; }
  int entries = ktN * 512;
  for (int e = threadIdx.x; e < entries; e += 256) {
    int kt = e >> 9, l = (e >> 3) & 63, jv = e & 7;
    int k = kt * 32 + ((l >> 4) << 3) + jv;
    int i = k >> 4, j = k & 15, n = l & 15;
    float w;
    if (dout1) w = (n == 0) ? Wsrc[i * 16 + j] : 0.f;   // W7 (16,16,1) -> col 0 only
    else       w = (i < din && j < din) ? Wsrc[(i * din + j) * 16 + n] : 0.f;
    uint u = __builtin_bit_cast(uint, w);
    uint h = u & 0xffff0000u;
    dst[e] = (ushort)(h >> 16);
    dst[entries + e] = rtn_bf16(w - __builtin_bit_cast(float, h));
  }
}

// ---------------- MFMA bilinear core -------------------------------------------
// One wave: C[16 b][16 d] = sum_k A[b,k] Wf[k,d], A[b, k=i*16+j] = l_i*r_j built
// in-register with exact trunc hi + trunc lo bf16 split (4 VALU/elem, v_perm pack).
// Lcol/Rcol: pointers to this lane's b-column; row stride ld.
// Wf: global or LDS frag blob (hi then lo), 16B-aligned slices.
template <int KTN, bool L0M>
__device__ __forceinline__ f32x4 mfma_core(const float* Lcol, const float* Rcol,
                                           int ld, const ushort* __restrict__ Wf,
                                           int lane) {
  const int g = lane >> 4;
  const int j0 = (g & 1) * 8, gh = g >> 1;
  float lf[2 * KTN];
#pragma unroll
  for (int i = 0; i < 2 * KTN; ++i) lf[i] = Lcol[i * ld];
  float rf[8];
#pragma unroll
  for (int j = 0; j < 8; ++j)
    rf[j] = (L0M && (j0 + j >= 9)) ? 0.f : Rcol[(j0 + j) * ld];
  f32x4 acc = {0.f, 0.f, 0.f, 0.f};
  const int entries = KTN * 512;
#pragma unroll
  for (int kt = 0; kt < KTN; ++kt) {
    const float li = lf[2 * kt + gh];
    u32x4 hv, lv;
#pragma unroll
    for (int jp = 0; jp < 4; ++jp) {
      float p0 = li * rf[2 * jp], p1 = li * rf[2 * jp + 1];
      uint u0 = __builtin_bit_cast(uint, p0);
      uint u1 = __builtin_bit_cast(uint, p1);
      float h0 = __builtin_bit_cast(float, u0 & 0xffff0000u);
      float h1 = __builtin_bit_cast(float, u1 & 0xffff0000u);
      float q0 = p0 - h0, q1 = p1 - h1;
      hv[jp] = __builtin_amdgcn_perm(u1, u0, 0x07060302u);                 // hi pack
      lv[jp] = __builtin_amdgcn_perm(__builtin_bit_cast(uint, q1),
                                     __builtin_bit_cast(uint, q0), 0x07060302u); // lo pack (trunc)
    }
    s16x8 ahi = __builtin_bit_cast(s16x8, hv);
    s16x8 alo = __builtin_bit_cast(s16x8, lv);
    const s16x8 wh = *(const s16x8*)&Wf[(kt * 64 + lane) * 8];
    const s16x8 wl = *(const s16x8*)&Wf[entries + (kt * 64 + lane) * 8];
    acc = __builtin_amdgcn_mfma_f32_16x16x32_bf16(ahi, wh, acc, 0, 0, 0);
    acc = __builtin_amdgcn_mfma_f32_16x16x32_bf16(alo, wh, acc, 0, 0, 0);
    acc = __builtin_amdgcn_mfma_f32_16x16x32_bf16(ahi, wl, acc, 0, 0, 0);
  }
  return acc;
}

__device__ __forceinline__ void feats_store(float xv, float* Fb, int bl) {
  float s1 = __sinf(xv), c1 = __cosf(xv);
  Fb[0 * 68 + bl] = 1.f; Fb[1 * 68 + bl] = s1; Fb[5 * 68 + bl] = c1;
  float sk = s1, ck = c1;
#pragma unroll
  for (int k = 2; k <= 4; ++k) {
    float sn = s1 * ck + c1 * sk, cn = c1 * ck - s1 * sk;
    sk = sn; ck = cn;
    Fb[k * 68 + bl] = sk; Fb[(4 + k) * 68 + bl] = ck;
  }
}

// ---------------- Levels 0-3 fused (depth-first over 16-leaf subtree) ----------
// Block: 256 thr / 4 waves / 64 b; W-frags read directly from L2 (no LDS stage).
// LDS ~36 KB -> 4 blocks/CU.
__global__ __launch_bounds__(256) void ttn_front_kernel(
    const float* __restrict__ x, const float* __restrict__ fminp,
    const ushort* __restrict__ U, float* __restrict__ s1out) {
  __shared__ __align__(16) float xt[64 * 17];
  __shared__ __align__(16) float F0[10 * 68], F1[10 * 68];
  __shared__ __align__(16) float A0[16 * 68], B0[16 * 68];
  __shared__ __align__(16) float A1[16 * 68], B1[16 * 68];
  __shared__ __align__(16) float A2[16 * 68], B2[16 * 68];

  const int tid = threadIdx.x;
  const int lane = tid & 63, w = tid >> 6;
  const int m = lane & 15, g = lane >> 4;
  const int bl = w * 16 + m;
  const int b0 = blockIdx.x * 64;
  const int s = blockIdx.y;
  const float fmin = fminp[0];

  { // stage x tile [64 b][16 leaves]
    int b_l = tid >> 2, fq = tid & 3;
    float4 v = *(const float4*)&x[(size_t)(b0 + b_l) * 256 + s * 16 + fq * 4];
    xt[b_l * 17 + fq * 4 + 0] = v.x;
    xt[b_l * 17 + fq * 4 + 1] = v.y;
    xt[b_l * 17 + fq * 4 + 2] = v.z;
    xt[b_l * 17 + fq * 4 + 3] = v.w;
  }
  if (tid < 68)       F0[9 * 68 + tid] = 0.f;          // zero pad row i=9
  else if (tid < 136) F1[9 * 68 + (tid - 68)] = 0.f;
  __syncthreads();

  float* outG = s1out + (size_t)(s * 16) * BTOT + b0;

  auto storeL = [&](f32x4 a, float* Out) {
#pragma unroll
    for (int r = 0; r < 4; ++r) Out[m * 68 + w * 16 + g * 4 + r] = a[r];
  };

  for (int t = 0; t < 8; ++t) {
    if (tid < 128) {
      int side = tid >> 6, b_l = tid & 63;
      float xv = xt[b_l * 17 + 2 * t + side] * fmin;
      feats_store(xv, side ? F1 : F0, b_l);
    }
    __syncthreads();
    f32x4 a = mfma_core<5, true>(&F0[bl], &F1[bl], 68,
                                 U + OFF0 + (size_t)(8 * s + t) * 5120, lane);
    storeL(a, (t & 1) ? B0 : A0);
    if (t & 1) {   // waves read only their own column slice -> no syncs needed
      f32x4 c1 = mfma_core<8, false>(&A0[bl], &B0[bl], 68,
                                     U + OFF1 + (size_t)(4 * s + (t >> 1)) * 8192, lane);
      storeL(c1, ((t >> 1) & 1) ? B1 : A1);
      if ((t & 3) == 3) {
        f32x4 c2 = mfma_core<8, false>(&A1[bl], &B1[bl], 68,
                                       U + OFF2 + (size_t)(2 * s + (t >> 2)) * 8192, lane);
        storeL(c2, ((t >> 2) & 1) ? B2 : A2);
        if (t == 7) {
          f32x4 c3 = mfma_core<8, false>(&A2[bl], &B2[bl], 68,
                                         U + OFF3 + (size_t)s * 8192, lane);
#pragma unroll
          for (int r = 0; r < 4; ++r)
            outG[(size_t)m * BTOT + w * 16 + g * 4 + r] = c3[r];
        }
      }
    }
    __syncthreads();   // guard next iter's F rewrite
  }
}

// ---------------- Levels 4-7 fused, one dispatch -------------------------------
// Block: 256 thr / 4 waves / 64 b. All 256 input rows staged once (64 KB LDS,
// in-place reuse). After staging, each wave touches only its own 16-b column
// slice -> zero syncthreads in the tree walk. Final W7 matvec = d=0-column MFMA.
__global__ __launch_bounds__(256) void ttn_back_kernel(
    const float* __restrict__ s1, const ushort* __restrict__ U,
    float* __restrict__ out) {
  __shared__ __align__(16) float T[256 * 64];
  const int tid = threadIdx.x;
  const int lane = tid & 63, w = tid >> 6;
  const int m = lane & 15, g = lane >> 4;
  const int bl = w * 16 + m;
  const int b0 = blockIdx.x * 64;

#pragma unroll
  for (int it = 0; it < 16; ++it) {       // stage [256 rows][64 b]
    int idx = it * 256 + tid;
    int r = idx >> 4, c4 = (idx & 15) << 2;
    float4 v = *(const float4*)&s1[(size_t)r * BTOT + b0 + c4];
    *(float4*)&T[r * 64 + c4] = v;
  }
  __syncthreads();

  // level 4: nodes 0..7, in rows [32n]+[32n+16], out rows [32n]
#pragma unroll
  for (int n = 0; n < 8; ++n) {
    f32x4 a = mfma_core<8, false>(&T[(32 * n) * 64 + bl], &T[(32 * n + 16) * 64 + bl],
                                  64, U + OFF4 + (size_t)n * 8192, lane);
#pragma unroll
    for (int r = 0; r < 4; ++r) T[(32 * n + m) * 64 + w * 16 + g * 4 + r] = a[r];
  }
  // level 5: nodes 0..3, in rows [64n]+[64n+32], out rows [64n]
#pragma unroll
  for (int n = 0; n < 4; ++n) {
    f32x4 a = mfma_core<8, false>(&T[(64 * n) * 64 + bl], &T[(64 * n + 32) * 64 + bl],
                                  64, U + OFF5 + (size_t)n * 8192, lane);
#pragma unroll
    for (int r = 0; r < 4; ++r) T[(64 * n + m) * 64 + w * 16 + g * 4 + r] = a[r];
  }
  // level 6: nodes 0..1, in rows [128n]+[128n+64], out rows [128n]
#pragma unroll
  for (int n = 0; n < 2; ++n) {
    f32x4 a = mfma_core<8, false>(&T[(128 * n) * 64 + bl], &T[(128 * n + 64) * 64 + bl],
                                  64, U + OFF6 + (size_t)n * 8192, lane);
#pragma unroll
    for (int r = 0; r < 4; ++r) T[(128 * n + m) * 64 + w * 16 + g * 4 + r] = a[r];
  }
  // level 7 (final, dout=1): W7-frag has only d=0 column nonzero
  {
    f32x4 a = mfma_core<8, false>(&T[bl], &T[128 * 64 + bl], 64, U + OFF7, lane);
    if (m == 0) {
#pragma unroll
      for (int r = 0; r < 4; ++r) out[b0 + w * 16 + g * 4 + r] = a[r];
    }
  }
}

extern "C" void kernel_launch(void* const* d_in, const int* in_sizes, int n_in,
                              void* d_out, int out_size, void* d_ws, size_t ws_size,
                              hipStream_t stream) {
  const float* x    = (const float*)d_in[0];
  const float* fmin = (const float*)d_in[1];
  const float* W0   = (const float*)d_in[2];
  const float* W1   = (const float*)d_in[3];
  const float* W2   = (const float*)d_in[4];
  const float* W3   = (const float*)d_in[5];
  const float* W4   = (const float*)d_in[6];
  const float* W5   = (const float*)d_in[7];
  const float* W6   = (const float*)d_in[8];
  const float* W7   = (const float*)d_in[9];
  float* out = (float*)d_out;

  // ws: [0,4MB) W-frags U | [4MB, +16.8MB) s1 intermediate
  ushort* U = (ushort*)d_ws;
  float* s1 = (float*)((char*)d_ws + (4u << 20));

  wprep_kernel<<<255, 256, 0, stream>>>(W0, W1, W2, W3, W4, W5, W6, W7, U);
  ttn_front_kernel<<<dim3(256, 16), 256, 0, stream>>>(x, fmin, U, s1);
  ttn_back_kernel<<<256, 256, 0, stream>>>(s1, U, out);
}

// Round 5
// 272.535 us; speedup vs baseline: 2.5116x; 1.3935x over previous
//
#include <hip/hip_runtime.h>
#include <math.h>

#define BTOT 16384

typedef __attribute__((ext_vector_type(8))) short s16x8;
typedef __attribute__((ext_vector_type(4))) float f32x4;
typedef __attribute__((ext_vector_type(4))) uint u32x4;
typedef __attribute__((ext_vector_type(2))) float f32x2;
typedef __attribute__((ext_vector_type(2))) uint u32x2;

// U region offsets (in ushorts). Per-node blob: [KTN*512 hi][KTN*512 lo].
#define OFF0 0u          // W0: 128 nodes x 5120
#define OFF1 655360u     // W1: 64 x 8192
#define OFF2 1179648u    // W2: 32 x 8192
#define OFF3 1441792u    // W3: 16 x 8192
#define OFF4 1572864u    // W4: 8 x 8192
#define OFF5 1638400u    // W5: 4 x 8192
#define OFF6 1671168u    // W6: 2 x 8192
#define OFF7 1687552u    // W7: 1 x 8192

__device__ __forceinline__ ushort rtn_bf16(float x) {
  uint u = __builtin_bit_cast(uint, x);
  uint r = u + 0x7fffu + ((u >> 16) & 1u);
  return (ushort)(r >> 16);
}

// ---------------- W-frag prep: all levels -> MFMA B-frag order, bf16 hi/lo ------
__global__ __launch_bounds__(256) void wprep_kernel(
    const float* __restrict__ W0, const float* __restrict__ W1,
    const float* __restrict__ W2, const float* __restrict__ W3,
    const float* __restrict__ W4, const float* __restrict__ W5,
    const float* __restrict__ W6, const float* __restrict__ W7,
    ushort* __restrict__ U) {
  int blk = blockIdx.x;
  const float* Wsrc; ushort* dst; int ktN, din; bool dout1 = false;
  if (blk < 128)      { Wsrc = W0 + blk * 1296;         dst = U + OFF0 + (size_t)blk * 5120;         ktN = 5; din = 9;  }
  else if (blk < 192) { Wsrc = W1 + (blk - 128) * 4096; dst = U + OFF1 + (size_t)(blk - 128) * 8192; ktN = 8; din = 16; }
  else if (blk < 224) { Wsrc = W2 + (blk - 192) * 4096; dst = U + OFF2 + (size_t)(blk - 192) * 8192; ktN = 8; din = 16; }
  else if (blk < 240) { Wsrc = W3 + (blk - 224) * 4096; dst = U + OFF3 + (size_t)(blk - 224) * 8192; ktN = 8; din = 16; }
  else if (blk < 248) { Wsrc = W4 + (blk - 240) * 4096; dst = U + OFF4 + (size_t)(blk - 240) * 8192; ktN = 8; din = 16; }
  else if (blk < 252) { Wsrc = W5 + (blk - 248) * 4096; dst = U + OFF5 + (size_t)(blk - 248) * 8192; ktN = 8; din = 16; }
  else if (blk < 254) { Wsrc = W6 + (blk - 252) * 4096; dst = U + OFF6 + (size_t)(blk - 252) * 8192; ktN = 8; din = 16; }
  else                { Wsrc = W7;                      dst = U + OFF7;                              ktN = 8; din = 16; dout1 = true; }
  int entries = ktN * 512;
  for (int e = threadIdx.x; e < entries; e += 256) {
    int kt = e >> 9, l = (e >> 3) & 63, jv = e & 7;
    int k = kt * 32 + ((l >> 4) << 3) + jv;
    int i = k >> 4, j = k & 15, n = l & 15;
    float w;
    if (dout1) w = (n == 0) ? Wsrc[i * 16 + j] : 0.f;
    else       w = (i < din && j < din) ? Wsrc[(i * din + j) * 16 + n] : 0.f;
    uint u = __builtin_bit_cast(uint, w);
    uint h = u & 0xffff0000u;
    dst[e] = (ushort)(h >> 16);
    dst[entries + e] = rtn_bf16(w - __builtin_bit_cast(float, h));
  }
}

// ---------------- MFMA bilinear core -------------------------------------------
// One wave: C[16 b][16 d] = sum_k A[b,k] W[k,d], A[b, k=i*16+j] = l_i*r_j.
// Split: hi = bit-trunc(p) (bias corrected exactly by residual), q = fma(l,r,-hi)
// (exact residual incl. mul rounding), lo = RTU(q) via +0x8000 (unbiased).
// Packed f32x2 math -> v_pk_mul/v_pk_fma where the backend supports it.
template <int KTN, bool L0M>
__device__ __forceinline__ f32x4 mfma_core(const float* Lcol, const float* Rcol,
                                           const int ld, const ushort* __restrict__ Wf,
                                           int lane) {
  const int g = lane >> 4;
  const int j0 = (g & 1) * 8, gh = g >> 1;
  const float* Lg = Lcol + gh * ld;
  float lf[KTN];
#pragma unroll
  for (int i = 0; i < KTN; ++i) lf[i] = Lg[2 * i * ld];   // only the 8 rows this lane needs
  f32x2 rf2[4];
#pragma unroll
  for (int j = 0; j < 8; ++j) {
    float v = (L0M && (j0 + j >= 9)) ? 0.f : Rcol[(j0 + j) * ld];
    rf2[j >> 1][j & 1] = v;
  }
  f32x4 acc = {0.f, 0.f, 0.f, 0.f};
  const int entries = KTN * 512;
#pragma unroll
  for (int kt = 0; kt < KTN; ++kt) {
    const f32x2 li2 = {lf[kt], lf[kt]};
    u32x4 hv, lv;
#pragma unroll
    for (int jp = 0; jp < 4; ++jp) {
      f32x2 p2 = li2 * rf2[jp];
      u32x2 u2 = __builtin_bit_cast(u32x2, p2);
      u32x2 hb = u2 & 0xffff0000u;
      f32x2 h2 = __builtin_bit_cast(f32x2, hb);
      f32x2 q2 = __builtin_elementwise_fma(li2, rf2[jp], -h2);
      u32x2 uq = __builtin_bit_cast(u32x2, q2) + 0x8000u;   // RTU de-bias
      hv[jp] = __builtin_amdgcn_perm(u2.y, u2.x, 0x07060302u);
      lv[jp] = __builtin_amdgcn_perm(uq.y, uq.x, 0x07060302u);
    }
    s16x8 ahi = __builtin_bit_cast(s16x8, hv);
    s16x8 alo = __builtin_bit_cast(s16x8, lv);
    const s16x8 wh = *(const s16x8*)&Wf[(kt * 64 + lane) * 8];
    const s16x8 wl = *(const s16x8*)&Wf[entries + (kt * 64 + lane) * 8];
    acc = __builtin_amdgcn_mfma_f32_16x16x32_bf16(ahi, wh, acc, 0, 0, 0);
    acc = __builtin_amdgcn_mfma_f32_16x16x32_bf16(alo, wh, acc, 0, 0, 0);
    acc = __builtin_amdgcn_mfma_f32_16x16x32_bf16(ahi, wl, acc, 0, 0, 0);
  }
  return acc;
}

__device__ __forceinline__ void feats_col(float xv, float* Fb, int col) {
  float s1 = __sinf(xv), c1 = __cosf(xv);
  Fb[0 * 68 + col] = 1.f; Fb[1 * 68 + col] = s1; Fb[5 * 68 + col] = c1;
  float sk = s1, ck = c1;
#pragma unroll
  for (int k = 2; k <= 4; ++k) {
    float sn = s1 * ck + c1 * sk, cn = c1 * ck - s1 * sk;
    sk = sn; ck = cn;
    Fb[k * 68 + col] = sk; Fb[(4 + k) * 68 + col] = ck;
  }
}

// ---------------- Levels 0-3 fused, zero-barrier (all LDS wave-private) --------
// Block: 256 thr / 4 waves; wave w owns b-subtile w*16..w*16+15 of the 64-b tile.
__global__ __launch_bounds__(256) void ttn_front_kernel(
    const float* __restrict__ x, const float* __restrict__ fminp,
    const ushort* __restrict__ U, float* __restrict__ s1out) {
  __shared__ __align__(16) float xt[64 * 17];
  __shared__ __align__(16) float F0[10 * 68], F1[10 * 68];
  __shared__ __align__(16) float A0[16 * 68], B0[16 * 68];
  __shared__ __align__(16) float A1[16 * 68], B1[16 * 68];
  __shared__ __align__(16) float A2[16 * 68], B2[16 * 68];

  const int tid = threadIdx.x;
  const int lane = tid & 63, w = tid >> 6;
  const int m = lane & 15, g = lane >> 4;
  const int bl = w * 16 + m;
  const int b0 = blockIdx.x * 64;
  const int s = blockIdx.y;
  const float fmin = fminp[0];

  { // stage x tile: wave-private rows
    int row = w * 16 + (lane >> 2), c4 = (lane & 3) * 4;
    float4 v = *(const float4*)&x[(size_t)(b0 + row) * 256 + s * 16 + c4];
    xt[row * 17 + c4 + 0] = v.x; xt[row * 17 + c4 + 1] = v.y;
    xt[row * 17 + c4 + 2] = v.z; xt[row * 17 + c4 + 3] = v.w;
  }
  if (lane < 32) { // zero pad row i=9 (wave-private cols)
    int col = w * 16 + (lane & 15);
    ((lane >> 4) ? F1 : F0)[9 * 68 + col] = 0.f;
  }

  float* outG = s1out + (size_t)(s * 16) * BTOT + b0;

  auto storeL = [&](f32x4 a, float* Out) {
#pragma unroll
    for (int r = 0; r < 4; ++r) Out[m * 68 + w * 16 + g * 4 + r] = a[r];
  };

  for (int t = 0; t < 8; ++t) {
    if (lane < 32) {   // wave-private feats: lane -> (b_loc, side)
      int b_loc = lane & 15, side = lane >> 4;
      float xv = xt[(w * 16 + b_loc) * 17 + 2 * t + side] * fmin;
      feats_col(xv, side ? F1 : F0, w * 16 + b_loc);
    }
    f32x4 a = mfma_core<5, true>(&F0[bl], &F1[bl], 68,
                                 U + OFF0 + (size_t)(8 * s + t) * 5120, lane);
    storeL(a, (t & 1) ? B0 : A0);
    if (t & 1) {
      f32x4 c1 = mfma_core<8, false>(&A0[bl], &B0[bl], 68,
                                     U + OFF1 + (size_t)(4 * s + (t >> 1)) * 8192, lane);
      storeL(c1, ((t >> 1) & 1) ? B1 : A1);
      if ((t & 3) == 3) {
        f32x4 c2 = mfma_core<8, false>(&A1[bl], &B1[bl], 68,
                                       U + OFF2 + (size_t)(2 * s + (t >> 2)) * 8192, lane);
        storeL(c2, ((t >> 2) & 1) ? B2 : A2);
        if (t == 7) {
          f32x4 c3 = mfma_core<8, false>(&A2[bl], &B2[bl], 68,
                                         U + OFF3 + (size_t)s * 8192, lane);
#pragma unroll
          for (int r = 0; r < 4; ++r)
            outG[(size_t)m * BTOT + w * 16 + g * 4 + r] = c3[r];
        }
      }
    }
  }
}

// ---------------- backA: levels 4+5. Wave = (16-b tile, L5-subtree), 4096 waves.
// In-place walk in a private 64x17 LDS region; zero barriers.
__global__ __launch_bounds__(256) void backA_kernel(
    const float* __restrict__ s1, const ushort* __restrict__ U,
    float* __restrict__ s2) {
  __shared__ __align__(16) float T[4][64 * 17];
  const int tid = threadIdx.x;
  const int lane = tid & 63, w = tid >> 6;
  const int m = lane & 15, g = lane >> 4;
  const int unit = blockIdx.x * 4 + w;
  const int tile = unit >> 2, n5 = unit & 3;
  const int b0 = tile * 16;
  float* Tw = T[w];

#pragma unroll
  for (int it = 0; it < 4; ++it) {        // stage 64 rows x 16 b
    int flat = it * 64 + lane;
    int r = flat >> 2, c4 = (flat & 3) * 4;
    float4 v = *(const float4*)&s1[(size_t)(n5 * 64 + r) * BTOT + b0 + c4];
    Tw[r * 17 + c4 + 0] = v.x; Tw[r * 17 + c4 + 1] = v.y;
    Tw[r * 17 + c4 + 2] = v.z; Tw[r * 17 + c4 + 3] = v.w;
  }
  // L4 node 2*n5: rows 0..15 x 16..31 -> rows 0..15
  f32x4 a0 = mfma_core<8, false>(&Tw[m], &Tw[16 * 17 + m], 17,
                                 U + OFF4 + (size_t)(2 * n5) * 8192, lane);
#pragma unroll
  for (int r = 0; r < 4; ++r) Tw[(0 + m) * 17 + g * 4 + r] = a0[r];
  // L4 node 2*n5+1: rows 32..47 x 48..63 -> rows 32..47
  f32x4 a1 = mfma_core<8, false>(&Tw[32 * 17 + m], &Tw[48 * 17 + m], 17,
                                 U + OFF4 + (size_t)(2 * n5 + 1) * 8192, lane);
#pragma unroll
  for (int r = 0; r < 4; ++r) Tw[(32 + m) * 17 + g * 4 + r] = a1[r];
  // L5 node n5: rows 0..15 x 32..47 -> global s2
  f32x4 a2 = mfma_core<8, false>(&Tw[m], &Tw[32 * 17 + m], 17,
                                 U + OFF5 + (size_t)n5 * 8192, lane);
#pragma unroll
  for (int r = 0; r < 4; ++r)
    s2[(size_t)(n5 * 16 + m) * BTOT + b0 + g * 4 + r] = a2[r];
}

// ---------------- backB: levels 6+7. Wave = 16-b tile, 1024 waves. -------------
__global__ __launch_bounds__(256) void backB_kernel(
    const float* __restrict__ s2, const ushort* __restrict__ U,
    float* __restrict__ out) {
  __shared__ __align__(16) float T[4][64 * 17];
  const int tid = threadIdx.x;
  const int lane = tid & 63, w = tid >> 6;
  const int m = lane & 15, g = lane >> 4;
  const int tile = blockIdx.x * 4 + w;
  const int b0 = tile * 16;
  float* Tw = T[w];

#pragma unroll
  for (int it = 0; it < 4; ++it) {        // stage all 64 s2 rows x 16 b
    int flat = it * 64 + lane;
    int r = flat >> 2, c4 = (flat & 3) * 4;
    float4 v = *(const float4*)&s2[(size_t)r * BTOT + b0 + c4];
    Tw[r * 17 + c4 + 0] = v.x; Tw[r * 17 + c4 + 1] = v.y;
    Tw[r * 17 + c4 + 2] = v.z; Tw[r * 17 + c4 + 3] = v.w;
  }
  // L6 node 0: rows 0..15 x 16..31 -> rows 0..15
  f32x4 a0 = mfma_core<8, false>(&Tw[m], &Tw[16 * 17 + m], 17, U + OFF6, lane);
#pragma unroll
  for (int r = 0; r < 4; ++r) Tw[(0 + m) * 17 + g * 4 + r] = a0[r];
  // L6 node 1: rows 32..47 x 48..63 -> rows 32..47
  f32x4 a1 = mfma_core<8, false>(&Tw[32 * 17 + m], &Tw[48 * 17 + m], 17,
                                 U + OFF6 + 8192, lane);
#pragma unroll
  for (int r = 0; r < 4; ++r) Tw[(32 + m) * 17 + g * 4 + r] = a1[r];
  // L7: rows 0..15 x 32..47, W7 frag nonzero only in d=0 column
  f32x4 a2 = mfma_core<8, false>(&Tw[m], &Tw[32 * 17 + m], 17, U + OFF7, lane);
  if (m == 0) {
#pragma unroll
    for (int r = 0; r < 4; ++r) out[b0 + g * 4 + r] = a2[r];
  }
}

extern "C" void kernel_launch(void* const* d_in, const int* in_sizes, int n_in,
                              void* d_out, int out_size, void* d_ws, size_t ws_size,
                              hipStream_t stream) {
  const float* x    = (const float*)d_in[0];
  const float* fmin = (const float*)d_in[1];
  const float* W0   = (const float*)d_in[2];
  const float* W1   = (const float*)d_in[3];
  const float* W2   = (const float*)d_in[4];
  const float* W3   = (const float*)d_in[5];
  const float* W4   = (const float*)d_in[6];
  const float* W5   = (const float*)d_in[7];
  const float* W6   = (const float*)d_in[8];
  const float* W7   = (const float*)d_in[9];
  float* out = (float*)d_out;

  // ws: [0,4MB) W-frags U | [4MB,+16.8MB) s1 | [+4.2MB) s2
  ushort* U = (ushort*)d_ws;
  float* s1 = (float*)((char*)d_ws + (4u << 20));
  float* s2 = (float*)((char*)d_ws + (4u << 20) + (size_t)16 * 16 * BTOT * 4);

  wprep_kernel<<<255, 256, 0, stream>>>(W0, W1, W2, W3, W4, W5, W6, W7, U);
  ttn_front_kernel<<<dim3(256, 16), 256, 0, stream>>>(x, fmin, U, s1);
  backA_kernel<<<1024, 256, 0, stream>>>(s1, U, s2);
  backB_kernel<<<256, 256, 0, stream>>>(s2, U, out);
}

// Round 6
// 249.667 us; speedup vs baseline: 2.7416x; 1.0916x over previous
//
#include <hip/hip_runtime.h>
#include <math.h>

#define BTOT 16384

typedef __attribute__((ext_vector_type(8))) short s16x8;
typedef __attribute__((ext_vector_type(4))) float f32x4;
typedef __attribute__((ext_vector_type(4))) uint u32x4;
typedef __attribute__((ext_vector_type(2))) float f32x2;
typedef __attribute__((ext_vector_type(2))) uint u32x2;

// U region offsets (in ushorts). Per-node blob: [KTN*512 hi][KTN*512 lo].
#define OFF0 0u          // W0: 128 nodes x 5120
#define OFF1 655360u     // W1: 64 x 8192
#define OFF2 1179648u    // W2: 32 x 8192
#define OFF3 1441792u    // W3: 16 x 8192
#define OFF4 1572864u    // W4: 8 x 8192
#define OFF5 1638400u    // W5: 4 x 8192
#define OFF6 1671168u    // W6: 2 x 8192
#define OFF7 1687552u    // W7: 1 x 8192

__device__ __forceinline__ ushort rtn_bf16(float x) {
  uint u = __builtin_bit_cast(uint, x);
  uint r = u + 0x7fffu + ((u >> 16) & 1u);
  return (ushort)(r >> 16);
}

// ---------------- W-frag prep: all levels -> MFMA B-frag order, bf16 hi/lo ------
__global__ __launch_bounds__(256) void wprep_kernel(
    const float* __restrict__ W0, const float* __restrict__ W1,
    const float* __restrict__ W2, const float* __restrict__ W3,
    const float* __restrict__ W4, const float* __restrict__ W5,
    const float* __restrict__ W6, const float* __restrict__ W7,
    ushort* __restrict__ U) {
  int blk = blockIdx.x;
  const float* Wsrc; ushort* dst; int ktN, din; bool dout1 = false;
  if (blk < 128)      { Wsrc = W0 + blk * 1296;         dst = U + OFF0 + (size_t)blk * 5120;         ktN = 5; din = 9;  }
  else if (blk < 192) { Wsrc = W1 + (blk - 128) * 4096; dst = U + OFF1 + (size_t)(blk - 128) * 8192; ktN = 8; din = 16; }
  else if (blk < 224) { Wsrc = W2 + (blk - 192) * 4096; dst = U + OFF2 + (size_t)(blk - 192) * 8192; ktN = 8; din = 16; }
  else if (blk < 240) { Wsrc = W3 + (blk - 224) * 4096; dst = U + OFF3 + (size_t)(blk - 224) * 8192; ktN = 8; din = 16; }
  else if (blk < 248) { Wsrc = W4 + (blk - 240) * 4096; dst = U + OFF4 + (size_t)(blk - 240) * 8192; ktN = 8; din = 16; }
  else if (blk < 252) { Wsrc = W5 + (blk - 248) * 4096; dst = U + OFF5 + (size_t)(blk - 248) * 8192; ktN = 8; din = 16; }
  else if (blk < 254) { Wsrc = W6 + (blk - 252) * 4096; dst = U + OFF6 + (size_t)(blk - 252) * 8192; ktN = 8; din = 16; }
  else                { Wsrc = W7;                      dst = U + OFF7;                              ktN = 8; din = 16; dout1 = true; }
  int entries = ktN * 512;
  for (int e = threadIdx.x; e < entries; e += 256) {
    int kt = e >> 9, l = (e >> 3) & 63, jv = e & 7;
    int k = kt * 32 + ((l >> 4) << 3) + jv;
    int i = k >> 4, j = k & 15, n = l & 15;
    float w;
    if (dout1) w = (n == 0) ? Wsrc[i * 16 + j] : 0.f;
    else       w = (i < din && j < din) ? Wsrc[(i * din + j) * 16 + n] : 0.f;
    uint u = __builtin_bit_cast(uint, w);
    uint h = u & 0xffff0000u;
    dst[e] = (ushort)(h >> 16);
    dst[entries + e] = rtn_bf16(w - __builtin_bit_cast(float, h));
  }
}

// ---------------- MFMA bilinear core -------------------------------------------
// One wave: C[16 b][16 d] = sum_k A[b,k] W[k,d], A[b, k=i*16+j] = l_i*r_j.
// hi = bit-trunc(p); q = fma(l,r,-hi) exact residual; lo = RTU(q) via +0x8000.
template <int KTN, bool L0M>
__device__ __forceinline__ f32x4 mfma_core(const float* Lcol, const float* Rcol,
                                           const int ld, const ushort* __restrict__ Wf,
                                           int lane) {
  const int g = lane >> 4;
  const int j0 = (g & 1) * 8, gh = g >> 1;
  const float* Lg = Lcol + gh * ld;
  float lf[KTN];
#pragma unroll
  for (int i = 0; i < KTN; ++i) lf[i] = Lg[2 * i * ld];
  f32x2 rf2[4];
#pragma unroll
  for (int j = 0; j < 8; ++j) {
    float v = (L0M && (j0 + j >= 9)) ? 0.f : Rcol[(j0 + j) * ld];
    rf2[j >> 1][j & 1] = v;
  }
  f32x4 acc = {0.f, 0.f, 0.f, 0.f};
  const int entries = KTN * 512;
#pragma unroll
  for (int kt = 0; kt < KTN; ++kt) {
    const s16x8 wh = *(const s16x8*)&Wf[(kt * 64 + lane) * 8];
    const s16x8 wl = *(const s16x8*)&Wf[entries + (kt * 64 + lane) * 8];
    const f32x2 li2 = {lf[kt], lf[kt]};
    u32x4 hv, lv;
#pragma unroll
    for (int jp = 0; jp < 4; ++jp) {
      f32x2 p2 = li2 * rf2[jp];
      u32x2 u2 = __builtin_bit_cast(u32x2, p2);
      u32x2 hb = u2 & 0xffff0000u;
      f32x2 h2 = __builtin_bit_cast(f32x2, hb);
      f32x2 q2 = __builtin_elementwise_fma(li2, rf2[jp], -h2);
      u32x2 uq = __builtin_bit_cast(u32x2, q2) + 0x8000u;   // RTU de-bias
      hv[jp] = __builtin_amdgcn_perm(u2.y, u2.x, 0x07060302u);
      lv[jp] = __builtin_amdgcn_perm(uq.y, uq.x, 0x07060302u);
    }
    s16x8 ahi = __builtin_bit_cast(s16x8, hv);
    s16x8 alo = __builtin_bit_cast(s16x8, lv);
    acc = __builtin_amdgcn_mfma_f32_16x16x32_bf16(ahi, wh, acc, 0, 0, 0);
    acc = __builtin_amdgcn_mfma_f32_16x16x32_bf16(alo, wh, acc, 0, 0, 0);
    acc = __builtin_amdgcn_mfma_f32_16x16x32_bf16(ahi, wl, acc, 0, 0, 0);
  }
  return acc;
}

#define LDF 67   // leading dim (floats): 67 % 32 = 3, coprime -> <=2-way conflicts

__device__ __forceinline__ void feats_col(float xv, float* Fb, int col) {
  float s1 = __sinf(xv), c1 = __cosf(xv);
  Fb[0 * LDF + col] = 1.f; Fb[1 * LDF + col] = s1; Fb[5 * LDF + col] = c1;
  float sk = s1, ck = c1;
#pragma unroll
  for (int k = 2; k <= 4; ++k) {
    float sn = s1 * ck + c1 * sk, cn = c1 * ck - s1 * sk;
    sk = sn; ck = cn;
    Fb[k * LDF + col] = sk; Fb[(4 + k) * LDF + col] = ck;
  }
}

// ---------------- Levels 0-3 fused, zero-barrier (all LDS wave-private) --------
// Block: 256 thr / 4 waves; LDS ~31 KB -> 5 blocks/CU (launch_bounds pins it).
__global__ __launch_bounds__(256, 5) void ttn_front_kernel(
    const float* __restrict__ x, const float* __restrict__ fminp,
    const ushort* __restrict__ U, float* __restrict__ s1out) {
  __shared__ float F0[10 * LDF], F1[10 * LDF];
  __shared__ float A0[16 * LDF], B0[16 * LDF];
  __shared__ float A1[16 * LDF], B1[16 * LDF];
  __shared__ float A2[16 * LDF], B2[16 * LDF];

  const int tid = threadIdx.x;
  const int lane = tid & 63, w = tid >> 6;
  const int m = lane & 15, g = lane >> 4;
  const int bl = w * 16 + m;
  const int b0 = blockIdx.x * 64;
  const int s = blockIdx.y;
  const float fmin = fminp[0];

  if (lane < 32) { // zero pad row i=9 (wave-private cols)
    int col = w * 16 + (lane & 15);
    ((lane >> 4) ? F1 : F0)[9 * LDF + col] = 0.f;
  }

  // per-lane x source: lane<32 handles (b_loc = lane&15, side = lane>>4);
  // each b's 16 leaves = one 64B line -> L1-resident across all t.
  const float* xw = x + (size_t)(b0 + w * 16 + (lane & 15)) * 256 + s * 16;
  float* outG = s1out + (size_t)(s * 16) * BTOT + b0;

  auto storeL = [&](f32x4 a, float* Out) {
#pragma unroll
    for (int r = 0; r < 4; ++r) Out[m * LDF + w * 16 + g * 4 + r] = a[r];
  };

  for (int t = 0; t < 8; ++t) {
    if (lane < 32) {
      int side = lane >> 4;
      float xv = xw[2 * t + side] * fmin;
      feats_col(xv, side ? F1 : F0, w * 16 + (lane & 15));
    }
    f32x4 a = mfma_core<5, true>(&F0[bl], &F1[bl], LDF,
                                 U + OFF0 + (size_t)(8 * s + t) * 5120, lane);
    storeL(a, (t & 1) ? B0 : A0);
    if (t & 1) {
      f32x4 c1 = mfma_core<8, false>(&A0[bl], &B0[bl], LDF,
                                     U + OFF1 + (size_t)(4 * s + (t >> 1)) * 8192, lane);
      storeL(c1, ((t >> 1) & 1) ? B1 : A1);
      if ((t & 3) == 3) {
        f32x4 c2 = mfma_core<8, false>(&A1[bl], &B1[bl], LDF,
                                       U + OFF2 + (size_t)(2 * s + (t >> 2)) * 8192, lane);
        storeL(c2, ((t >> 2) & 1) ? B2 : A2);
        if (t == 7) {
          f32x4 c3 = mfma_core<8, false>(&A2[bl], &B2[bl], LDF,
                                         U + OFF3 + (size_t)s * 8192, lane);
#pragma unroll
          for (int r = 0; r < 4; ++r)
            outG[(size_t)m * BTOT + w * 16 + g * 4 + r] = c3[r];
        }
      }
    }
  }
}

// ---------------- Levels 4-7 fused, one dispatch -------------------------------
// Block = one 16-b tile (256 thr / 4 waves). Wave q: L4 nodes 2q,2q+1 (independent
// -> ILP) then L5 node q, all in wave-private rows. Barrier; waves 0,1 do L6;
// barrier; wave 0 does L7. Rows [256][17] in LDS, ld=17 conflict-free.
__global__ __launch_bounds__(256) void ttn_back_kernel(
    const float* __restrict__ s1, const ushort* __restrict__ U,
    float* __restrict__ out) {
  __shared__ float T[256 * 17];
  const int tid = threadIdx.x;
  const int lane = tid & 63, w = tid >> 6;
  const int m = lane & 15, g = lane >> 4;
  const int b0 = blockIdx.x * 16;

#pragma unroll
  for (int it = 0; it < 4; ++it) {      // stage [256 rows][16 b]
    int idx = it * 256 + tid;
    int r = idx >> 2, c4 = (idx & 3) * 4;
    float4 v = *(const float4*)&s1[(size_t)r * BTOT + b0 + c4];
    T[r * 17 + c4 + 0] = v.x; T[r * 17 + c4 + 1] = v.y;
    T[r * 17 + c4 + 2] = v.z; T[r * 17 + c4 + 3] = v.w;
  }
  __syncthreads();

  const int q = w, base = 64 * q;
  // L4 node 2q: rows base..+15 x base+16..+31 -> rows base
  f32x4 a0 = mfma_core<8, false>(&T[base * 17 + m], &T[(base + 16) * 17 + m], 17,
                                 U + OFF4 + (size_t)(2 * q) * 8192, lane);
  // L4 node 2q+1: rows base+32 x base+48 -> rows base+32
  f32x4 a1 = mfma_core<8, false>(&T[(base + 32) * 17 + m], &T[(base + 48) * 17 + m], 17,
                                 U + OFF4 + (size_t)(2 * q + 1) * 8192, lane);
#pragma unroll
  for (int r = 0; r < 4; ++r) {
    T[(base + m) * 17 + g * 4 + r] = a0[r];
    T[(base + 32 + m) * 17 + g * 4 + r] = a1[r];
  }
  // L5 node q: rows base x base+32 -> rows base
  f32x4 a2 = mfma_core<8, false>(&T[base * 17 + m], &T[(base + 32) * 17 + m], 17,
                                 U + OFF5 + (size_t)q * 8192, lane);
#pragma unroll
  for (int r = 0; r < 4; ++r) T[(base + m) * 17 + g * 4 + r] = a2[r];
  __syncthreads();

  if (w < 2) {  // L6 node w: rows 128w x 128w+64 -> rows 128w
    f32x4 a3 = mfma_core<8, false>(&T[(128 * w) * 17 + m], &T[(128 * w + 64) * 17 + m],
                                   17, U + OFF6 + (size_t)w * 8192, lane);
#pragma unroll
    for (int r = 0; r < 4; ++r) T[(128 * w + m) * 17 + g * 4 + r] = a3[r];
  }
  __syncthreads();

  if (w == 0) { // L7: rows 0 x 128; W7-frag nonzero only in d=0 column
    f32x4 a4 = mfma_core<8, false>(&T[m], &T[128 * 17 + m], 17, U + OFF7, lane);
    if (m == 0) {
#pragma unroll
      for (int r = 0; r < 4; ++r) out[b0 + g * 4 + r] = a4[r];
    }
  }
}

extern "C" void kernel_launch(void* const* d_in, const int* in_sizes, int n_in,
                              void* d_out, int out_size, void* d_ws, size_t ws_size,
                              hipStream_t stream) {
  const float* x    = (const float*)d_in[0];
  const float* fmin = (const float*)d_in[1];
  const float* W0   = (const float*)d_in[2];
  const float* W1   = (const float*)d_in[3];
  const float* W2   = (const float*)d_in[4];
  const float* W3   = (const float*)d_in[5];
  const float* W4   = (const float*)d_in[6];
  const float* W5   = (const float*)d_in[7];
  const float* W6   = (const float*)d_in[8];
  const float* W7   = (const float*)d_in[9];
  float* out = (float*)d_out;

  // ws: [0,4MB) W-frags U | [4MB,+16.8MB) s1
  ushort* U = (ushort*)d_ws;
  float* s1 = (float*)((char*)d_ws + (4u << 20));

  wprep_kernel<<<255, 256, 0, stream>>>(W0, W1, W2, W3, W4, W5, W6, W7, U);
  ttn_front_kernel<<<dim3(256, 16), 256, 0, stream>>>(x, fmin, U, s1);
  ttn_back_kernel<<<1024, 256, 0, stream>>>(s1, U, out);
}

// Round 7
// 237.138 us; speedup vs baseline: 2.8865x; 1.0528x over previous
//
#include <hip/hip_runtime.h>
#include <math.h>

#define BTOT 16384

typedef __attribute__((ext_vector_type(8))) short s16x8;
typedef __attribute__((ext_vector_type(4))) float f32x4;
typedef __attribute__((ext_vector_type(4))) uint u32x4;
typedef __attribute__((ext_vector_type(2))) float f32x2;
typedef __attribute__((ext_vector_type(2))) uint u32x2;

// U region offsets (in ushorts). Per-node blob: [KTN*512 hi][KTN*512 lo].
#define OFF0 0u          // W0: 128 nodes x 5120
#define OFF1 655360u     // W1: 64 x 8192
#define OFF2 1179648u    // W2: 32 x 8192
#define OFF3 1441792u    // W3: 16 x 8192
#define OFF4 1572864u    // W4: 8 x 8192
#define OFF5 1638400u    // W5: 4 x 8192
#define OFF6 1671168u    // W6: 2 x 8192
#define OFF7 1687552u    // W7: 1 x 8192

__device__ __forceinline__ ushort rtn_bf16(float x) {
  uint u = __builtin_bit_cast(uint, x);
  uint r = u + 0x7fffu + ((u >> 16) & 1u);
  return (ushort)(r >> 16);
}

// ---------------- W-frag prep: all levels -> MFMA B-frag order, bf16 hi/lo ------
__global__ __launch_bounds__(256) void wprep_kernel(
    const float* __restrict__ W0, const float* __restrict__ W1,
    const float* __restrict__ W2, const float* __restrict__ W3,
    const float* __restrict__ W4, const float* __restrict__ W5,
    const float* __restrict__ W6, const float* __restrict__ W7,
    ushort* __restrict__ U) {
  int blk = blockIdx.x;
  const float* Wsrc; ushort* dst; int ktN, din; bool dout1 = false;
  if (blk < 128)      { Wsrc = W0 + blk * 1296;         dst = U + OFF0 + (size_t)blk * 5120;         ktN = 5; din = 9;  }
  else if (blk < 192) { Wsrc = W1 + (blk - 128) * 4096; dst = U + OFF1 + (size_t)(blk - 128) * 8192; ktN = 8; din = 16; }
  else if (blk < 224) { Wsrc = W2 + (blk - 192) * 4096; dst = U + OFF2 + (size_t)(blk - 192) * 8192; ktN = 8; din = 16; }
  else if (blk < 240) { Wsrc = W3 + (blk - 224) * 4096; dst = U + OFF3 + (size_t)(blk - 224) * 8192; ktN = 8; din = 16; }
  else if (blk < 248) { Wsrc = W4 + (blk - 240) * 4096; dst = U + OFF4 + (size_t)(blk - 240) * 8192; ktN = 8; din = 16; }
  else if (blk < 252) { Wsrc = W5 + (blk - 248) * 4096; dst = U + OFF5 + (size_t)(blk - 248) * 8192; ktN = 8; din = 16; }
  else if (blk < 254) { Wsrc = W6 + (blk - 252) * 4096; dst = U + OFF6 + (size_t)(blk - 252) * 8192; ktN = 8; din = 16; }
  else                { Wsrc = W7;                      dst = U + OFF7;                              ktN = 8; din = 16; dout1 = true; }
  int entries = ktN * 512;
  for (int e = threadIdx.x; e < entries; e += 256) {
    int kt = e >> 9, l = (e >> 3) & 63, jv = e & 7;
    int k = kt * 32 + ((l >> 4) << 3) + jv;
    int i = k >> 4, j = k & 15, n = l & 15;
    float w;
    if (dout1) w = (n == 0) ? Wsrc[i * 16 + j] : 0.f;
    else       w = (i < din && j < din) ? Wsrc[(i * din + j) * 16 + n] : 0.f;
    uint u = __builtin_bit_cast(uint, w);
    uint h = u & 0xffff0000u;
    dst[e] = (ushort)(h >> 16);
    dst[entries + e] = rtn_bf16(w - __builtin_bit_cast(float, h));
  }
}

// ---------------- MFMA bilinear core -------------------------------------------
// One wave: C[16 b][16 d] = sum_k A[b,k] W[k,d], A[b, k=i*16+j] = l_i*r_j.
// hi = bit-trunc(p); lo = trunc(fma(l,r,-hi)) — exact residual, trunc pack.
// (R4 measured this arithmetic at absmax 7.1e-15 vs 2.17e-14 threshold.)
template <int KTN, bool L0M>
__device__ __forceinline__ f32x4 mfma_core(const float* Lcol, const float* Rcol,
                                           const int ld, const ushort* __restrict__ Wf,
                                           int lane) {
  const int g = lane >> 4;
  const int j0 = (g & 1) * 8, gh = g >> 1;
  const float* Lg = Lcol + gh * ld;
  float lf[KTN];
#pragma unroll
  for (int i = 0; i < KTN; ++i) lf[i] = Lg[2 * i * ld];
  f32x2 rf2[4];
#pragma unroll
  for (int j = 0; j < 8; ++j) {
    float v = (L0M && (j0 + j >= 9)) ? 0.f : Rcol[(j0 + j) * ld];
    rf2[j >> 1][j & 1] = v;
  }
  f32x4 acc = {0.f, 0.f, 0.f, 0.f};
  const int entries = KTN * 512;
#pragma unroll
  for (int kt = 0; kt < KTN; ++kt) {
    const s16x8 wh = *(const s16x8*)&Wf[(kt * 64 + lane) * 8];
    const s16x8 wl = *(const s16x8*)&Wf[entries + (kt * 64 + lane) * 8];
    const f32x2 li2 = {lf[kt], lf[kt]};
    u32x4 hv, lv;
#pragma unroll
    for (int jp = 0; jp < 4; ++jp) {
      f32x2 p2 = li2 * rf2[jp];
      u32x2 u2 = __builtin_bit_cast(u32x2, p2);
      u32x2 hb = u2 & 0xffff0000u;
      f32x2 h2 = __builtin_bit_cast(f32x2, hb);
      f32x2 q2 = __builtin_elementwise_fma(li2, rf2[jp], -h2);
      u32x2 uq = __builtin_bit_cast(u32x2, q2);
      hv[jp] = __builtin_amdgcn_perm(u2.y, u2.x, 0x07060302u);
      lv[jp] = __builtin_amdgcn_perm(uq.y, uq.x, 0x07060302u);
    }
    s16x8 ahi = __builtin_bit_cast(s16x8, hv);
    s16x8 alo = __builtin_bit_cast(s16x8, lv);
    acc = __builtin_amdgcn_mfma_f32_16x16x32_bf16(ahi, wh, acc, 0, 0, 0);
    acc = __builtin_amdgcn_mfma_f32_16x16x32_bf16(alo, wh, acc, 0, 0, 0);
    acc = __builtin_amdgcn_mfma_f32_16x16x32_bf16(ahi, wl, acc, 0, 0, 0);
  }
  return acc;
}

#define LDF 67   // leading dim (floats): 67 % 32 = 3, coprime -> <=2-way conflicts

__device__ __forceinline__ void feats_col(float xv, float* Fb, int col) {
  float s1 = __sinf(xv), c1 = __cosf(xv);
  Fb[0 * LDF + col] = 1.f; Fb[1 * LDF + col] = s1; Fb[5 * LDF + col] = c1;
  float sk = s1, ck = c1;
#pragma unroll
  for (int k = 2; k <= 4; ++k) {
    float sn = s1 * ck + c1 * sk, cn = c1 * ck - s1 * sk;
    sk = sn; ck = cn;
    Fb[k * LDF + col] = sk; Fb[(4 + k) * LDF + col] = ck;
  }
}

// ---------------- Levels 0-3 fused, zero-barrier (all LDS wave-private) --------
// Block: 256 thr / 4 waves; LDS ~31 KB. (256,4): VGPR cap 128 -> NO SPILL
// (R6's (256,5) pinned VGPR=48 and spilled: WRITE_SIZE 16->60 MB).
__global__ __launch_bounds__(256, 4) void ttn_front_kernel(
    const float* __restrict__ x, const float* __restrict__ fminp,
    const ushort* __restrict__ U, float* __restrict__ s1out) {
  __shared__ float F0[10 * LDF], F1[10 * LDF];
  __shared__ float A0[16 * LDF], B0[16 * LDF];
  __shared__ float A1[16 * LDF], B1[16 * LDF];
  __shared__ float A2[16 * LDF], B2[16 * LDF];

  const int tid = threadIdx.x;
  const int lane = tid & 63, w = tid >> 6;
  const int m = lane & 15, g = lane >> 4;
  const int bl = w * 16 + m;
  const int b0 = blockIdx.x * 64;
  const int s = blockIdx.y;
  const float fmin = fminp[0];

  if (lane < 32) { // zero pad row i=9 (wave-private cols)
    int col = w * 16 + (lane & 15);
    ((lane >> 4) ? F1 : F0)[9 * LDF + col] = 0.f;
  }

  // per-lane x source: lane<32 handles (b_loc = lane&15, side = lane>>4);
  // each b's 16 leaves = one 64B line -> L1-resident across all t.
  const float* xw = x + (size_t)(b0 + w * 16 + (lane & 15)) * 256 + s * 16;
  float* outG = s1out + (size_t)(s * 16) * BTOT + b0;

  auto storeL = [&](f32x4 a, float* Out) {
#pragma unroll
    for (int r = 0; r < 4; ++r) Out[m * LDF + w * 16 + g * 4 + r] = a[r];
  };

  for (int t = 0; t < 8; ++t) {
    if (lane < 32) {
      int side = lane >> 4;
      float xv = xw[2 * t + side] * fmin;
      feats_col(xv, side ? F1 : F0, w * 16 + (lane & 15));
    }
    f32x4 a = mfma_core<5, true>(&F0[bl], &F1[bl], LDF,
                                 U + OFF0 + (size_t)(8 * s + t) * 5120, lane);
    storeL(a, (t & 1) ? B0 : A0);
    if (t & 1) {
      f32x4 c1 = mfma_core<8, false>(&A0[bl], &B0[bl], LDF,
                                     U + OFF1 + (size_t)(4 * s + (t >> 1)) * 8192, lane);
      storeL(c1, ((t >> 1) & 1) ? B1 : A1);
      if ((t & 3) == 3) {
        f32x4 c2 = mfma_core<8, false>(&A1[bl], &B1[bl], LDF,
                                       U + OFF2 + (size_t)(2 * s + (t >> 2)) * 8192, lane);
        storeL(c2, ((t >> 2) & 1) ? B2 : A2);
        if (t == 7) {
          f32x4 c3 = mfma_core<8, false>(&A2[bl], &B2[bl], LDF,
                                         U + OFF3 + (size_t)s * 8192, lane);
#pragma unroll
          for (int r = 0; r < 4; ++r)
            outG[(size_t)m * BTOT + w * 16 + g * 4 + r] = c3[r];
        }
      }
    }
  }
}

// ---------------- Levels 4-7 fused, one dispatch -------------------------------
// Block = one 16-b tile (256 thr / 4 waves). Wave q: L4 nodes 2q,2q+1 (independent
// -> ILP) then L5 node q, all in wave-private rows. Barrier; waves 0,1 do L6;
// barrier; wave 0 does L7. Rows [256][17] in LDS, ld=17 conflict-free.
__global__ __launch_bounds__(256) void ttn_back_kernel(
    const float* __restrict__ s1, const ushort* __restrict__ U,
    float* __restrict__ out) {
  __shared__ float T[256 * 17];
  const int tid = threadIdx.x;
  const int lane = tid & 63, w = tid >> 6;
  const int m = lane & 15, g = lane >> 4;
  const int b0 = blockIdx.x * 16;

#pragma unroll
  for (int it = 0; it < 4; ++it) {      // stage [256 rows][16 b]
    int idx = it * 256 + tid;
    int r = idx >> 2, c4 = (idx & 3) * 4;
    float4 v = *(const float4*)&s1[(size_t)r * BTOT + b0 + c4];
    T[r * 17 + c4 + 0] = v.x; T[r * 17 + c4 + 1] = v.y;
    T[r * 17 + c4 + 2] = v.z; T[r * 17 + c4 + 3] = v.w;
  }
  __syncthreads();

  const int q = w, base = 64 * q;
  // L4 node 2q: rows base..+15 x base+16..+31 -> rows base
  f32x4 a0 = mfma_core<8, false>(&T[base * 17 + m], &T[(base + 16) * 17 + m], 17,
                                 U + OFF4 + (size_t)(2 * q) * 8192, lane);
  // L4 node 2q+1: rows base+32 x base+48 -> rows base+32
  f32x4 a1 = mfma_core<8, false>(&T[(base + 32) * 17 + m], &T[(base + 48) * 17 + m], 17,
                                 U + OFF4 + (size_t)(2 * q + 1) * 8192, lane);
#pragma unroll
  for (int r = 0; r < 4; ++r) {
    T[(base + m) * 17 + g * 4 + r] = a0[r];
    T[(base + 32 + m) * 17 + g * 4 + r] = a1[r];
  }
  // L5 node q: rows base x base+32 -> rows base
  f32x4 a2 = mfma_core<8, false>(&T[base * 17 + m], &T[(base + 32) * 17 + m], 17,
                                 U + OFF5 + (size_t)q * 8192, lane);
#pragma unroll
  for (int r = 0; r < 4; ++r) T[(base + m) * 17 + g * 4 + r] = a2[r];
  __syncthreads();

  if (w < 2) {  // L6 node w: rows 128w x 128w+64 -> rows 128w
    f32x4 a3 = mfma_core<8, false>(&T[(128 * w) * 17 + m], &T[(128 * w + 64) * 17 + m],
                                   17, U + OFF6 + (size_t)w * 8192, lane);
#pragma unroll
    for (int r = 0; r < 4; ++r) T[(128 * w + m) * 17 + g * 4 + r] = a3[r];
  }
  __syncthreads();

  if (w == 0) { // L7: rows 0 x 128; W7-frag nonzero only in d=0 column
    f32x4 a4 = mfma_core<8, false>(&T[m], &T[128 * 17 + m], 17, U + OFF7, lane);
    if (m == 0) {
#pragma unroll
      for (int r = 0; r < 4; ++r) out[b0 + g * 4 + r] = a4[r];
    }
  }
}

extern "C" void kernel_launch(void* const* d_in, const int* in_sizes, int n_in,
                              void* d_out, int out_size, void* d_ws, size_t ws_size,
                              hipStream_t stream) {
  const float* x    = (const float*)d_in[0];
  const float* fmin = (const float*)d_in[1];
  const float* W0   = (const float*)d_in[2];
  const float* W1   = (const float*)d_in[3];
  const float* W2   = (const float*)d_in[4];
  const float* W3   = (const float*)d_in[5];
  const float* W4   = (const float*)d_in[6];
  const float* W5   = (const float*)d_in[7];
  const float* W6   = (const float*)d_in[8];
  const float* W7   = (const float*)d_in[9];
  float* out = (float*)d_out;

  // ws: [0,4MB) W-frags U | [4MB,+16.8MB) s1
  ushort* U = (ushort*)d_ws;
  float* s1 = (float*)((char*)d_ws + (4u << 20));

  wprep_kernel<<<255, 256, 0, stream>>>(W0, W1, W2, W3, W4, W5, W6, W7, U);
  ttn_front_kernel<<<dim3(256, 16), 256, 0, stream>>>(x, fmin, U, s1);
  ttn_back_kernel<<<1024, 256, 0, stream>>>(s1, U, out);
}